// Round 16
// baseline (48.453 us; speedup 1.0000x reference)
//
#include <hip/hip_runtime.h>
#include <hip/hip_bf16.h>

typedef __attribute__((ext_vector_type(8))) short bf16x8;
typedef __attribute__((ext_vector_type(4))) short s16x4;
typedef __attribute__((ext_vector_type(4))) float fx4;

#define MFMA16(a, b, c) __builtin_amdgcn_mfma_f32_16x16x32_bf16((a), (b), (c), 0, 0, 0)

__device__ __forceinline__ short f2bf(float f) {
  unsigned u = __float_as_uint(f);
  u += 0x7fffu + ((u >> 16) & 1u);   // round-to-nearest-even
  return (short)(u >> 16);
}

// unaligned-tolerant 16B load (V patch reads are only 4B-aligned)
__device__ __forceinline__ bf16x8 ldu16(const short* p) {
  bf16x8 v; __builtin_memcpy(&v, p, 16); return v;
}

// async global->LDS, 16B per lane; LDS dest is wave-uniform base + lane*16B
__device__ __forceinline__ void gl_lds16(const short* g, short* l) {
  __builtin_amdgcn_global_load_lds((const __attribute__((address_space(1))) void*)(g),
                                   (__attribute__((address_space(3))) void*)(l), 16, 0, 0);
}

// ---------------- kernel 0: f32 -> bf16 conversion ----------------
__global__ __launch_bounds__(256) void convert_k(
    const float* __restrict__ x, const float* __restrict__ wq, const float* __restrict__ wo,
    short* __restrict__ xb, short* __restrict__ wb, short* __restrict__ wob) {
  const int i4 = (blockIdx.x * 256 + threadIdx.x) * 4;
  {
    float4 v = *(const float4*)(x + i4);
    s16x4 s; s[0] = f2bf(v.x); s[1] = f2bf(v.y); s[2] = f2bf(v.z); s[3] = f2bf(v.w);
    *(s16x4*)(xb + i4) = s;
  }
  if (i4 < 1152 * 384) {
    float4 v = *(const float4*)(wq + i4);
    s16x4 s; s[0] = f2bf(v.x); s[1] = f2bf(v.y); s[2] = f2bf(v.z); s[3] = f2bf(v.w);
    *(s16x4*)(wb + i4) = s;
  }
  if (i4 < 384 * 384) {
    float4 v = *(const float4*)(wo + i4);
    s16x4 s; s[0] = f2bf(v.x); s[1] = f2bf(v.y); s[2] = f2bf(v.z); s[3] = f2bf(v.w);
    *(s16x4*)(wob + i4) = s;
  }
}

// ---------------- kernel 1: qkv = x @ w_qkv^T, scatter q/k ([pix][d]) and v ([d][pix]) ---
// 64x128 tile, BK=128 -> 3 K-steps (3 barrier-drains instead of 6), 48 KB LDS (3/CU).
// 16 chunks/row, XOR swizzle phys = c ^ (row&7) (bit3 preserved; banks fully spread).
__global__ __launch_bounds__(256) void qkv_gemm(
    const short* __restrict__ A, const short* __restrict__ Bw,
    short* __restrict__ qb, short* __restrict__ kb, short* __restrict__ vb) {
  __shared__ __align__(16) short As[64 * 128];    // 16 KB
  __shared__ __align__(16) short Bs[128 * 128];   // 32 KB
  const int orig = (blockIdx.x & 7) * 144 + (blockIdx.x >> 3);  // 1152 = 8*144
  const int mt = orig / 9, nt = orig % 9;
  const int m0 = mt * 64, n0 = nt * 128;
  const int tid = threadIdx.x;
  const int lane = tid & 63, w = tid >> 6;
  const int wr = w >> 1, wc = w & 1;                 // wave: 32 rows x 64 cols
  const int l15 = lane & 15, l4 = lane >> 4;
  // staging: one gload = 4 rows x 16 chunks; srow4 = row-in-4, sc16 = data chunk
  const int srow4 = lane >> 4, sc16 = lane & 15;
  const fx4 vzero = {0.f, 0.f, 0.f, 0.f};
  fx4 acc[2][4];
#pragma unroll
  for (int i = 0; i < 2; i++)
#pragma unroll
    for (int j = 0; j < 4; j++) acc[i][j] = vzero;

  for (int kt = 0; kt < 384; kt += 128) {
    __syncthreads();
    // A rows [w*16, w*16+16): 4 gloads x 4 rows
#pragma unroll
    for (int q = 0; q < 4; q++) {
      const int row = w * 16 + q * 4 + srow4;
      gl_lds16(A + (size_t)(m0 + row) * 384 + kt + ((sc16 ^ (row & 7)) * 8), As + (w * 16 + q * 4) * 128);
    }
    // B rows [w*32, w*32+32): 8 gloads x 4 rows
#pragma unroll
    for (int q = 0; q < 8; q++) {
      const int row = w * 32 + q * 4 + srow4;
      gl_lds16(Bw + (size_t)(n0 + row) * 384 + kt + ((sc16 ^ (row & 7)) * 8), Bs + (w * 32 + q * 4) * 128);
    }
    __syncthreads();
    bf16x8 af[2][4], bfr[4][4];
#pragma unroll
    for (int i = 0; i < 2; i++) {
      const int ra = wr * 32 + i * 16 + l15;
#pragma unroll
      for (int kk = 0; kk < 4; kk++)
        af[i][kk] = *(const bf16x8*)(As + ra * 128 + (((kk * 4 + l4) ^ (ra & 7)) * 8));
    }
#pragma unroll
    for (int j = 0; j < 4; j++) {
      const int rb = wc * 64 + j * 16 + l15;
#pragma unroll
      for (int kk = 0; kk < 4; kk++)
        bfr[j][kk] = *(const bf16x8*)(Bs + rb * 128 + (((kk * 4 + l4) ^ (rb & 7)) * 8));
    }
#pragma unroll
    for (int i = 0; i < 2; i++)
#pragma unroll
      for (int j = 0; j < 4; j++)
#pragma unroll
        for (int kk = 0; kk < 4; kk++)
          acc[i][j] = MFMA16(af[i][kk], bfr[j][kk], acc[i][j]);
  }
  // epilogue: e = t*384 + head*64 + d
  // q,k -> [b][head][pix][64] ; v -> [b][head][64][pix] (d-major, for natt direct loads)
#pragma unroll
  for (int j = 0; j < 4; j++) {
    const int e = n0 + wc * 64 + j * 16 + l15;
    const int t = e / 384;
    const int rem = e - t * 384;
    const int head = rem >> 6, d = rem & 63;
#pragma unroll
    for (int i = 0; i < 2; i++) {
      const int mb = m0 + wr * 32 + i * 16 + l4 * 4;   // multiple of 4
      const int b = mb >> 12, pix = mb & 4095;
      if (t == 2) {
        s16x4 s4;
#pragma unroll
        for (int r = 0; r < 4; r++) s4[r] = f2bf(acc[i][j][r]);
        *(s16x4*)(vb + ((size_t)(b * 6 + head) * 64 + d) * 4096 + pix) = s4;
      } else {
        short* __restrict__ dst = (t == 0) ? qb : kb;
#pragma unroll
        for (int r = 0; r < 4; r++)
          dst[((size_t)(b * 6 + head) * 4096 + pix + r) * 64 + d] = f2bf(acc[i][j][r]);
      }
    }
  }
}

// ---------------- kernel 2: neighbourhood attention ----------------
// K staged in LDS (reused as Ps); V direct from d-major global; per-wave 8-row key window.
__global__ __launch_bounds__(256) void natt_k(
    const short* __restrict__ qg, const short* __restrict__ kg, const short* __restrict__ vtg,
    short* __restrict__ ob) {
  __shared__ __align__(16) short lds[224 * 72];  // 32.3 KB; Ks, then reused as Ps
  short* Ks = lds;           // [224][72]  (kk = kr*16+kc, d)
  short* Ps = lds;           // [64][136]  (q, local slot) -- overlays Ks after QK phase

  const int bid = (blockIdx.x & 7) * 96 + (blockIdx.x >> 3);   // 768/8 = 96
  const int tile = bid & 63, bh = bid >> 6;
  const int h0 = (tile >> 3) * 8, w0 = (tile & 7) * 8;
  const int ph0 = max(h0 - 3, 0);
  const int pw0 = min(max(w0 - 3, 0) & ~1, 48);  // even + 16-col slot grid stays in-row
  const int prows = min(h0 + 4, 57) + 7 - ph0;   // <= 14
  const int pcols = min(w0 + 4, 57) + 7 - pw0;   // <= 16
  const short* kb  = kg  + (size_t)bh * 262144;
  const short* vtb = vtg + (size_t)bh * 262144;  // [d][pix]
  const short* qb  = qg  + (size_t)bh * 262144;
  const int tid = threadIdx.x;
  const int lane = tid & 63, w = tid >> 6;
  const int l15 = lane & 15, l4 = lane >> 4;

  // wave's key-row window start: sh evaluated at query row 2w (wave-uniform)
  const int nlo = min(max(h0 + 2 * w - 3, 0), 57) - ph0;

  // Q fragments hoisted ABOVE staging
  const int qa = w * 16 + l15;
  const int qpix = (h0 + (qa >> 3)) * 64 + (w0 + (qa & 7));
  const bf16x8 aq0 = *(const bf16x8*)(qb + qpix * 64 + l4 * 8);
  const bf16x8 aq1 = *(const bf16x8*)(qb + qpix * 64 + 32 + l4 * 8);

  // stage K [224][72] (vector writes, adjacent lanes -> contiguous chunks)
  for (int i = tid; i < 224 * 8; i += 256) {
    const int kk = i >> 3, dc = i & 7;
    const int kr = kk >> 4, kc = kk & 15;
    const int krc = min(kr, prows - 1), kcc = min(kc, pcols - 1);
    const int pix = (ph0 + krc) * 64 + (pw0 + kcc);
    *(bf16x8*)(Ks + kk * 72 + dc * 8) = *(const bf16x8*)(kb + pix * 64 + dc * 8);
  }
  __syncthreads();

  const fx4 vzero = {0.f, 0.f, 0.f, 0.f};
  fx4 s[8];
#pragma unroll
  for (int nj = 0; nj < 8; nj++) s[nj] = vzero;
#pragma unroll
  for (int nj = 0; nj < 8; nj++) {
    const int n = nlo + nj;
    const bf16x8 b0 = *(const bf16x8*)(Ks + (n * 16 + l15) * 72 + l4 * 8);
    const bf16x8 b1 = *(const bf16x8*)(Ks + (n * 16 + l15) * 72 + 32 + l4 * 8);
    s[nj] = MFMA16(aq0, b0, s[nj]);
    s[nj] = MFMA16(aq1, b1, s[nj]);
  }

  // masked softmax in registers; lane owns rows q = w*16 + l4*4 + r, key col = l15
#pragma unroll
  for (int r = 0; r < 4; r++) {
    const int q = w * 16 + l4 * 4 + r;
    const int qh = h0 + (q >> 3), qw = w0 + (q & 7);
    const int sh = min(max(qh - 3, 0), 57) - ph0;
    const int sw = min(max(qw - 3, 0), 57) - pw0;
    float m = -1e30f;
#pragma unroll
    for (int nj = 0; nj < 8; nj++) {
      const int n = nlo + nj;
      const bool valid = (n >= sh) && (n < sh + 7) && (l15 >= sw) && (l15 < sw + 7);
      const float val = valid ? s[nj][r] * 0.125f : -1e30f;
      s[nj][r] = val;
      m = fmaxf(m, val);
    }
    m = fmaxf(m, __shfl_xor(m, 1));
    m = fmaxf(m, __shfl_xor(m, 2));
    m = fmaxf(m, __shfl_xor(m, 4));
    m = fmaxf(m, __shfl_xor(m, 8));
    float sum = 0.f;
#pragma unroll
    for (int nj = 0; nj < 8; nj++) {
      const float e = __expf(s[nj][r] - m);
      s[nj][r] = e;
      sum += e;
    }
    sum += __shfl_xor(sum, 1);
    sum += __shfl_xor(sum, 2);
    sum += __shfl_xor(sum, 4);
    sum += __shfl_xor(sum, 8);
    const float inv = 1.f / sum;
#pragma unroll
    for (int nj = 0; nj < 8; nj++) s[nj][r] *= inv;
  }

  __syncthreads();  // all QK reads of Ks done -> safe to overlay Ps

  // P -> LDS, local slot index (wave-local rows)
#pragma unroll
  for (int nj = 0; nj < 8; nj++)
#pragma unroll
    for (int r = 0; r < 4; r++)
      Ps[(w * 16 + l4 * 4 + r) * 136 + nj * 16 + l15] = f2bf(s[nj][r]);

  __builtin_amdgcn_wave_barrier();

  // PV: V fragments direct from d-major global [d][pix]
  fx4 o[4];
#pragma unroll
  for (int j = 0; j < 4; j++) o[j] = vzero;
#pragma unroll
  for (int ks = 0; ks < 4; ks++) {
    const bf16x8 pa = *(const bf16x8*)(Ps + (w * 16 + l15) * 136 + ks * 32 + l4 * 8);
    const int n = nlo + 2 * ks + (l4 >> 1);
    const int vp = (ph0 + min(n, prows - 1)) * 64 + pw0 + (l4 & 1) * 8;
#pragma unroll
    for (int j = 0; j < 4; j++) {
      const bf16x8 vf = ldu16(vtb + (size_t)(j * 16 + l15) * 4096 + vp);
      o[j] = MFMA16(pa, vf, o[j]);
    }
  }

  const int b = bh / 6, head = bh % 6;
#pragma unroll
  for (int j = 0; j < 4; j++) {
    const int d = j * 16 + l15;
#pragma unroll
    for (int r = 0; r < 4; r++) {
      const int q = w * 16 + l4 * 4 + r;
      const int pix = (h0 + (q >> 3)) * 64 + (w0 + (q & 7));
      ob[(size_t)(b * 4096 + pix) * 384 + head * 64 + d] = f2bf(o[j][r]);
    }
  }
}

// ---------------- kernel 3: out = attn_out @ w_out^T (f32 output) ----------------
// 64x64 tile -> 768 blocks (exactly 3/CU), BK=64, swizzled gload_lds (R13 form)
__global__ __launch_bounds__(256) void out_gemm(
    const short* __restrict__ A, const short* __restrict__ Bw, float* __restrict__ out) {
  __shared__ __align__(16) short As[64 * 64];    // 8 KB
  __shared__ __align__(16) short Bs[64 * 64];    // 8 KB
  const int orig = (blockIdx.x & 7) * 96 + (blockIdx.x >> 3);  // 768 = 8*96
  const int mt = orig / 6, nt = orig % 6;
  const int m0 = mt * 64, n0 = nt * 64;
  const int tid = threadIdx.x;
  const int lane = tid & 63, w = tid >> 6;
  const int wr = w >> 1, wc = w & 1;        // wave: 32 rows x 32 cols
  const int l15 = lane & 15, l4 = lane >> 4;
  const int srow = lane >> 3;
  const int scol = ((lane & 7) ^ (srow & 7)) * 8;
  const fx4 vzero = {0.f, 0.f, 0.f, 0.f};
  fx4 acc[2][2];
#pragma unroll
  for (int i = 0; i < 2; i++)
#pragma unroll
    for (int j = 0; j < 2; j++) acc[i][j] = vzero;

  for (int kt = 0; kt < 384; kt += 64) {
    __syncthreads();
#pragma unroll
    for (int q = 0; q < 2; q++) {
      gl_lds16(A  + (size_t)(m0 + w * 16 + q * 8 + srow) * 384 + kt + scol, As + (w * 16 + q * 8) * 64);
      gl_lds16(Bw + (size_t)(n0 + w * 16 + q * 8 + srow) * 384 + kt + scol, Bs + (w * 16 + q * 8) * 64);
    }
    __syncthreads();
    bf16x8 af[2][2], bfr[2][2];
#pragma unroll
    for (int i = 0; i < 2; i++) {
      const int ra = wr * 32 + i * 16 + l15;
#pragma unroll
      for (int kk = 0; kk < 2; kk++)
        af[i][kk] = *(const bf16x8*)(As + ra * 64 + (((kk * 4 + l4) ^ (ra & 7)) * 8));
    }
#pragma unroll
    for (int j = 0; j < 2; j++) {
      const int rb = wc * 32 + j * 16 + l15;
#pragma unroll
      for (int kk = 0; kk < 2; kk++)
        bfr[j][kk] = *(const bf16x8*)(Bs + rb * 64 + (((kk * 4 + l4) ^ (rb & 7)) * 8));
    }
#pragma unroll
    for (int i = 0; i < 2; i++)
#pragma unroll
      for (int j = 0; j < 2; j++) {
        acc[i][j] = MFMA16(af[i][0], bfr[j][0], acc[i][j]);
        acc[i][j] = MFMA16(af[i][1], bfr[j][1], acc[i][j]);
      }
  }
#pragma unroll
  for (int j = 0; j < 2; j++) {
    const int e = n0 + wc * 32 + j * 16 + l15;
#pragma unroll
    for (int i = 0; i < 2; i++) {
      const int mb = m0 + wr * 32 + i * 16 + l4 * 4;
#pragma unroll
      for (int r = 0; r < 4; r++)
        out[(size_t)(mb + r) * 384 + e] = acc[i][j][r];
    }
  }
}

extern "C" void kernel_launch(void* const* d_in, const int* in_sizes, int n_in,
                              void* d_out, int out_size, void* d_ws, size_t ws_size,
                              hipStream_t stream) {
  const float* x  = (const float*)d_in[0];
  const float* wq = (const float*)d_in[1];
  const float* wo = (const float*)d_in[2];
  float* out = (float*)d_out;

  short* xb  = (short*)d_ws;            // 8192*384
  short* wb  = xb + 8192 * 384;         // 1152*384
  short* wob = wb + 1152 * 384;         // 384*384
  short* qb  = wob + 384 * 384;         // 12*4096*64
  short* kb  = qb + 3145728;
  short* vb  = kb + 3145728;            // v in [b][head][64][4096] (d-major)
  short* ob  = vb + 3145728;            // 8192*384
  // total: ~32.6 MB of d_ws

  convert_k<<<3072, 256, 0, stream>>>(x, wq, wo, xb, wb, wob);
  qkv_gemm<<<1152, 256, 0, stream>>>(xb, wb, qb, kb, vb);
  natt_k<<<768, 256, 0, stream>>>(qb, kb, vb, ob);
  out_gemm<<<768, 256, 0, stream>>>(ob, wob, out);
}

// Round 17
// 45.991 us; speedup vs baseline: 1.0535x; 1.0535x over previous
//
#include <hip/hip_runtime.h>
#include <hip/hip_bf16.h>

typedef __attribute__((ext_vector_type(8))) short bf16x8;
typedef __attribute__((ext_vector_type(4))) short s16x4;
typedef __attribute__((ext_vector_type(4))) float fx4;

#define MFMA16(a, b, c) __builtin_amdgcn_mfma_f32_16x16x32_bf16((a), (b), (c), 0, 0, 0)

__device__ __forceinline__ short f2bf(float f) {
  unsigned u = __float_as_uint(f);
  u += 0x7fffu + ((u >> 16) & 1u);   // round-to-nearest-even
  return (short)(u >> 16);
}

// unaligned-tolerant 16B load (V patch reads are only 4B-aligned)
__device__ __forceinline__ bf16x8 ldu16(const short* p) {
  bf16x8 v; __builtin_memcpy(&v, p, 16); return v;
}

// async global->LDS, 16B per lane; LDS dest is wave-uniform base + lane*16B
__device__ __forceinline__ void gl_lds16(const short* g, short* l) {
  __builtin_amdgcn_global_load_lds((const __attribute__((address_space(1))) void*)(g),
                                   (__attribute__((address_space(3))) void*)(l), 16, 0, 0);
}

// ---------------- kernel 0: f32 -> bf16 conversion ----------------
__global__ __launch_bounds__(256) void convert_k(
    const float* __restrict__ x, const float* __restrict__ wq, const float* __restrict__ wo,
    short* __restrict__ xb, short* __restrict__ wb, short* __restrict__ wob) {
  const int i4 = (blockIdx.x * 256 + threadIdx.x) * 4;
  {
    float4 v = *(const float4*)(x + i4);
    s16x4 s; s[0] = f2bf(v.x); s[1] = f2bf(v.y); s[2] = f2bf(v.z); s[3] = f2bf(v.w);
    *(s16x4*)(xb + i4) = s;
  }
  if (i4 < 1152 * 384) {
    float4 v = *(const float4*)(wq + i4);
    s16x4 s; s[0] = f2bf(v.x); s[1] = f2bf(v.y); s[2] = f2bf(v.z); s[3] = f2bf(v.w);
    *(s16x4*)(wb + i4) = s;
  }
  if (i4 < 384 * 384) {
    float4 v = *(const float4*)(wo + i4);
    s16x4 s; s[0] = f2bf(v.x); s[1] = f2bf(v.y); s[2] = f2bf(v.z); s[3] = f2bf(v.w);
    *(s16x4*)(wob + i4) = s;
  }
}

// ---------------- kernel 1: qkv = x @ w_qkv^T, scatter q/k ([pix][d]) and v ([d][pix]) ---
// 64x128 tile -> 1152 blocks, BK=64, XOR-swizzled gload_lds (proven 46.0 form)
__global__ __launch_bounds__(256) void qkv_gemm(
    const short* __restrict__ A, const short* __restrict__ Bw,
    short* __restrict__ qb, short* __restrict__ kb, short* __restrict__ vb) {
  __shared__ __align__(16) short As[64 * 64];    // 8 KB
  __shared__ __align__(16) short Bs[128 * 64];   // 16 KB
  const int orig = (blockIdx.x & 7) * 144 + (blockIdx.x >> 3);  // 1152 = 8*144
  const int mt = orig / 9, nt = orig % 9;
  const int m0 = mt * 64, n0 = nt * 128;
  const int tid = threadIdx.x;
  const int lane = tid & 63, w = tid >> 6;
  const int wr = w >> 1, wc = w & 1;                 // wave: 32 rows x 64 cols
  const int l15 = lane & 15, l4 = lane >> 4;
  const int srow = lane >> 3;                          // row within 8-row stage group
  const int scol = ((lane & 7) ^ (srow & 7)) * 8;      // inverse-swizzled source col
  const fx4 vzero = {0.f, 0.f, 0.f, 0.f};
  fx4 acc[2][4];
#pragma unroll
  for (int i = 0; i < 2; i++)
#pragma unroll
    for (int j = 0; j < 4; j++) acc[i][j] = vzero;

  for (int kt = 0; kt < 384; kt += 64) {
    __syncthreads();
#pragma unroll
    for (int q = 0; q < 2; q++)
      gl_lds16(A + (size_t)(m0 + w * 16 + q * 8 + srow) * 384 + kt + scol, As + (w * 16 + q * 8) * 64);
#pragma unroll
    for (int q = 0; q < 4; q++)
      gl_lds16(Bw + (size_t)(n0 + w * 32 + q * 8 + srow) * 384 + kt + scol, Bs + (w * 32 + q * 8) * 64);
    __syncthreads();
    bf16x8 af[2][2], bfr[4][2];
#pragma unroll
    for (int i = 0; i < 2; i++) {
      const int ra = wr * 32 + i * 16 + l15;
#pragma unroll
      for (int kk = 0; kk < 2; kk++)
        af[i][kk] = *(const bf16x8*)(As + ra * 64 + (((kk * 4 + l4) ^ (ra & 7)) * 8));
    }
#pragma unroll
    for (int j = 0; j < 4; j++) {
      const int rb = wc * 64 + j * 16 + l15;
#pragma unroll
      for (int kk = 0; kk < 2; kk++)
        bfr[j][kk] = *(const bf16x8*)(Bs + rb * 64 + (((kk * 4 + l4) ^ (rb & 7)) * 8));
    }
#pragma unroll
    for (int i = 0; i < 2; i++)
#pragma unroll
      for (int j = 0; j < 4; j++) {
        acc[i][j] = MFMA16(af[i][0], bfr[j][0], acc[i][j]);
        acc[i][j] = MFMA16(af[i][1], bfr[j][1], acc[i][j]);
      }
  }
  // epilogue: e = t*384 + head*64 + d
  // q,k -> [b][head][pix][64] ; v -> [b][head][64][pix] (d-major, for natt direct loads)
#pragma unroll
  for (int j = 0; j < 4; j++) {
    const int e = n0 + wc * 64 + j * 16 + l15;
    const int t = e / 384;
    const int rem = e - t * 384;
    const int head = rem >> 6, d = rem & 63;
#pragma unroll
    for (int i = 0; i < 2; i++) {
      const int mb = m0 + wr * 32 + i * 16 + l4 * 4;   // multiple of 4
      const int b = mb >> 12, pix = mb & 4095;
      if (t == 2) {
        s16x4 s4;
#pragma unroll
        for (int r = 0; r < 4; r++) s4[r] = f2bf(acc[i][j][r]);
        *(s16x4*)(vb + ((size_t)(b * 6 + head) * 64 + d) * 4096 + pix) = s4;
      } else {
        short* __restrict__ dst = (t == 0) ? qb : kb;
#pragma unroll
        for (int r = 0; r < 4; r++)
          dst[((size_t)(b * 6 + head) * 4096 + pix + r) * 64 + d] = f2bf(acc[i][j][r]);
      }
    }
  }
}

// ---------------- kernel 2: neighbourhood attention ----------------
// K staged in LDS (reused as Ps); V direct from d-major global; per-wave 8-row key window.
__global__ __launch_bounds__(256) void natt_k(
    const short* __restrict__ qg, const short* __restrict__ kg, const short* __restrict__ vtg,
    short* __restrict__ ob) {
  __shared__ __align__(16) short lds[224 * 72];  // 32.3 KB; Ks, then reused as Ps
  short* Ks = lds;           // [224][72]  (kk = kr*16+kc, d)
  short* Ps = lds;           // [64][136]  (q, local slot) -- overlays Ks after QK phase

  const int bid = (blockIdx.x & 7) * 96 + (blockIdx.x >> 3);   // 768/8 = 96
  const int tile = bid & 63, bh = bid >> 6;
  const int h0 = (tile >> 3) * 8, w0 = (tile & 7) * 8;
  const int ph0 = max(h0 - 3, 0);
  const int pw0 = min(max(w0 - 3, 0) & ~1, 48);  // even + 16-col slot grid stays in-row
  const int prows = min(h0 + 4, 57) + 7 - ph0;   // <= 14
  const int pcols = min(w0 + 4, 57) + 7 - pw0;   // <= 16
  const short* kb  = kg  + (size_t)bh * 262144;
  const short* vtb = vtg + (size_t)bh * 262144;  // [d][pix]
  const short* qb  = qg  + (size_t)bh * 262144;
  const int tid = threadIdx.x;
  const int lane = tid & 63, w = tid >> 6;
  const int l15 = lane & 15, l4 = lane >> 4;

  // wave's key-row window start: sh evaluated at query row 2w (wave-uniform)
  const int nlo = min(max(h0 + 2 * w - 3, 0), 57) - ph0;

  // Q fragments hoisted ABOVE staging
  const int qa = w * 16 + l15;
  const int qpix = (h0 + (qa >> 3)) * 64 + (w0 + (qa & 7));
  const bf16x8 aq0 = *(const bf16x8*)(qb + qpix * 64 + l4 * 8);
  const bf16x8 aq1 = *(const bf16x8*)(qb + qpix * 64 + 32 + l4 * 8);

  // stage K [224][72] (vector writes, adjacent lanes -> contiguous chunks)
  for (int i = tid; i < 224 * 8; i += 256) {
    const int kk = i >> 3, dc = i & 7;
    const int kr = kk >> 4, kc = kk & 15;
    const int krc = min(kr, prows - 1), kcc = min(kc, pcols - 1);
    const int pix = (ph0 + krc) * 64 + (pw0 + kcc);
    *(bf16x8*)(Ks + kk * 72 + dc * 8) = *(const bf16x8*)(kb + pix * 64 + dc * 8);
  }
  __syncthreads();

  const fx4 vzero = {0.f, 0.f, 0.f, 0.f};
  fx4 s[8];
#pragma unroll
  for (int nj = 0; nj < 8; nj++) s[nj] = vzero;
#pragma unroll
  for (int nj = 0; nj < 8; nj++) {
    const int n = nlo + nj;
    const bf16x8 b0 = *(const bf16x8*)(Ks + (n * 16 + l15) * 72 + l4 * 8);
    const bf16x8 b1 = *(const bf16x8*)(Ks + (n * 16 + l15) * 72 + 32 + l4 * 8);
    s[nj] = MFMA16(aq0, b0, s[nj]);
    s[nj] = MFMA16(aq1, b1, s[nj]);
  }

  // masked softmax in registers; lane owns rows q = w*16 + l4*4 + r, key col = l15
#pragma unroll
  for (int r = 0; r < 4; r++) {
    const int q = w * 16 + l4 * 4 + r;
    const int qh = h0 + (q >> 3), qw = w0 + (q & 7);
    const int sh = min(max(qh - 3, 0), 57) - ph0;
    const int sw = min(max(qw - 3, 0), 57) - pw0;
    float m = -1e30f;
#pragma unroll
    for (int nj = 0; nj < 8; nj++) {
      const int n = nlo + nj;
      const bool valid = (n >= sh) && (n < sh + 7) && (l15 >= sw) && (l15 < sw + 7);
      const float val = valid ? s[nj][r] * 0.125f : -1e30f;
      s[nj][r] = val;
      m = fmaxf(m, val);
    }
    m = fmaxf(m, __shfl_xor(m, 1));
    m = fmaxf(m, __shfl_xor(m, 2));
    m = fmaxf(m, __shfl_xor(m, 4));
    m = fmaxf(m, __shfl_xor(m, 8));
    float sum = 0.f;
#pragma unroll
    for (int nj = 0; nj < 8; nj++) {
      const float e = __expf(s[nj][r] - m);
      s[nj][r] = e;
      sum += e;
    }
    sum += __shfl_xor(sum, 1);
    sum += __shfl_xor(sum, 2);
    sum += __shfl_xor(sum, 4);
    sum += __shfl_xor(sum, 8);
    const float inv = 1.f / sum;
#pragma unroll
    for (int nj = 0; nj < 8; nj++) s[nj][r] *= inv;
  }

  __syncthreads();  // all QK reads of Ks done -> safe to overlay Ps

  // P -> LDS, local slot index (wave-local rows)
#pragma unroll
  for (int nj = 0; nj < 8; nj++)
#pragma unroll
    for (int r = 0; r < 4; r++)
      Ps[(w * 16 + l4 * 4 + r) * 136 + nj * 16 + l15] = f2bf(s[nj][r]);

  __builtin_amdgcn_wave_barrier();

  // PV: V fragments direct from d-major global [d][pix]
  fx4 o[4];
#pragma unroll
  for (int j = 0; j < 4; j++) o[j] = vzero;
#pragma unroll
  for (int ks = 0; ks < 4; ks++) {
    const bf16x8 pa = *(const bf16x8*)(Ps + (w * 16 + l15) * 136 + ks * 32 + l4 * 8);
    const int n = nlo + 2 * ks + (l4 >> 1);
    const int vp = (ph0 + min(n, prows - 1)) * 64 + pw0 + (l4 & 1) * 8;
#pragma unroll
    for (int j = 0; j < 4; j++) {
      const bf16x8 vf = ldu16(vtb + (size_t)(j * 16 + l15) * 4096 + vp);
      o[j] = MFMA16(pa, vf, o[j]);
    }
  }

  const int b = bh / 6, head = bh % 6;
#pragma unroll
  for (int j = 0; j < 4; j++) {
    const int d = j * 16 + l15;
#pragma unroll
    for (int r = 0; r < 4; r++) {
      const int q = w * 16 + l4 * 4 + r;
      const int pix = (h0 + (q >> 3)) * 64 + (w0 + (q & 7));
      ob[(size_t)(b * 4096 + pix) * 384 + head * 64 + d] = f2bf(o[j][r]);
    }
  }
}

// ---------------- kernel 3: out = attn_out @ w_out^T (f32 output) ----------------
// 64x64 tile -> 768 blocks (exactly 3/CU), BK=64, swizzled gload_lds
__global__ __launch_bounds__(256) void out_gemm(
    const short* __restrict__ A, const short* __restrict__ Bw, float* __restrict__ out) {
  __shared__ __align__(16) short As[64 * 64];    // 8 KB
  __shared__ __align__(16) short Bs[64 * 64];    // 8 KB
  const int orig = (blockIdx.x & 7) * 96 + (blockIdx.x >> 3);  // 768 = 8*96
  const int mt = orig / 6, nt = orig % 6;
  const int m0 = mt * 64, n0 = nt * 64;
  const int tid = threadIdx.x;
  const int lane = tid & 63, w = tid >> 6;
  const int wr = w >> 1, wc = w & 1;        // wave: 32 rows x 32 cols
  const int l15 = lane & 15, l4 = lane >> 4;
  const int srow = lane >> 3;
  const int scol = ((lane & 7) ^ (srow & 7)) * 8;
  const fx4 vzero = {0.f, 0.f, 0.f, 0.f};
  fx4 acc[2][2];
#pragma unroll
  for (int i = 0; i < 2; i++)
#pragma unroll
    for (int j = 0; j < 2; j++) acc[i][j] = vzero;

  for (int kt = 0; kt < 384; kt += 64) {
    __syncthreads();
#pragma unroll
    for (int q = 0; q < 2; q++) {
      gl_lds16(A  + (size_t)(m0 + w * 16 + q * 8 + srow) * 384 + kt + scol, As + (w * 16 + q * 8) * 64);
      gl_lds16(Bw + (size_t)(n0 + w * 16 + q * 8 + srow) * 384 + kt + scol, Bs + (w * 16 + q * 8) * 64);
    }
    __syncthreads();
    bf16x8 af[2][2], bfr[2][2];
#pragma unroll
    for (int i = 0; i < 2; i++) {
      const int ra = wr * 32 + i * 16 + l15;
#pragma unroll
      for (int kk = 0; kk < 2; kk++)
        af[i][kk] = *(const bf16x8*)(As + ra * 64 + (((kk * 4 + l4) ^ (ra & 7)) * 8));
    }
#pragma unroll
    for (int j = 0; j < 2; j++) {
      const int rb = wc * 32 + j * 16 + l15;
#pragma unroll
      for (int kk = 0; kk < 2; kk++)
        bfr[j][kk] = *(const bf16x8*)(Bs + rb * 64 + (((kk * 4 + l4) ^ (rb & 7)) * 8));
    }
#pragma unroll
    for (int i = 0; i < 2; i++)
#pragma unroll
      for (int j = 0; j < 2; j++) {
        acc[i][j] = MFMA16(af[i][0], bfr[j][0], acc[i][j]);
        acc[i][j] = MFMA16(af[i][1], bfr[j][1], acc[i][j]);
      }
  }
#pragma unroll
  for (int j = 0; j < 2; j++) {
    const int e = n0 + wc * 32 + j * 16 + l15;
#pragma unroll
    for (int i = 0; i < 2; i++) {
      const int mb = m0 + wr * 32 + i * 16 + l4 * 4;
#pragma unroll
      for (int r = 0; r < 4; r++)
        out[(size_t)(mb + r) * 384 + e] = acc[i][j][r];
    }
  }
}

extern "C" void kernel_launch(void* const* d_in, const int* in_sizes, int n_in,
                              void* d_out, int out_size, void* d_ws, size_t ws_size,
                              hipStream_t stream) {
  const float* x  = (const float*)d_in[0];
  const float* wq = (const float*)d_in[1];
  const float* wo = (const float*)d_in[2];
  float* out = (float*)d_out;

  short* xb  = (short*)d_ws;            // 8192*384
  short* wb  = xb + 8192 * 384;         // 1152*384
  short* wob = wb + 1152 * 384;         // 384*384
  short* qb  = wob + 384 * 384;         // 12*4096*64
  short* kb  = qb + 3145728;
  short* vb  = kb + 3145728;            // v in [b][head][64][4096] (d-major)
  short* ob  = vb + 3145728;            // 8192*384
  // total: ~32.6 MB of d_ws

  convert_k<<<3072, 256, 0, stream>>>(x, wq, wo, xb, wb, wob);
  qkv_gemm<<<1152, 256, 0, stream>>>(xb, wb, qb, kb, vb);
  natt_k<<<768, 256, 0, stream>>>(qb, kb, vb, ob);
  out_gemm<<<768, 256, 0, stream>>>(ob, wob, out);
}